// Round 9
// baseline (282.056 us; speedup 1.0000x reference)
//
#include <hip/hip_runtime.h>
#include <math.h>

#define D_MODEL 1024
#define NHEADS  16
#define DK      64
#define BATCH   2
#define SEQ     2048
#define M_TOTAL (BATCH * SEQ)   // 4096
#define NT128   (SEQ / 128)     // 16 k-tiles of 128
// Q is PRE-SCALED by 0.125*log2e in the QKV GEMM epilogue, so flash softmax
// is P = mask ? exp2(S) : 0 (shift-invariant; S <= 12*log2e -> exp2 <= 1.7e5).
#define QSCALE 0.18033688011112042f

typedef __attribute__((ext_vector_type(8))) short bf16x8;  // 8 bf16 (4 VGPRs)
typedef __attribute__((ext_vector_type(4))) float f32x4;   // MFMA C/D

// ---- fp32 -> bf16 (RNE) ----------------------------------------------------
__device__ __forceinline__ unsigned short f2bf(float f) {
    union { float f; unsigned int i; } v; v.f = f;
    return (unsigned short)((v.i + 0x7FFFu + ((v.i >> 16) & 1u)) >> 16);
}

// ---- async global->LDS, 16 B per lane (dest = wave-uniform base + lane*16) --
__device__ __forceinline__ void async_copy16(const void* g, void* l) {
    __builtin_amdgcn_global_load_lds(
        (const __attribute__((address_space(1))) unsigned int*)g,
        (__attribute__((address_space(3))) unsigned int*)l, 16, 0, 0);
}

// ---------------------------------------------------------------------------
// prep_all: W transposes + mask pack ONLY (Q/K/V fp32->bf16 conversion moved
// INTO the QKV GEMM's A-staging — saves 75 MB of prep traffic + 12288 blocks).
//   blocks [0,4096):     W [k][n] fp32 -> WT [n][k] bf16 (1024 per z, 4 z)
//   blocks [4096,6144):  mask -> packed 64-bit lane masks (swapped-QK layout)
// ---------------------------------------------------------------------------
struct PrepArgs {
    const float* wsrc[4]; unsigned short* wdst[4];  // Wq/Wk/Wv/Wo transpose cvt
    const int* mask; unsigned long long* wm;        // mask pack
};

__global__ __launch_bounds__(256)
void prep_all(const PrepArgs a)
{
    __shared__ unsigned short tbuf[32][33];
    const int id  = blockIdx.x;
    const int tid = threadIdx.x;

    if (id < 4096) {
        const int z  = id >> 10;
        const int rem = id & 1023;
        const int bx = rem & 31;
        const int by = rem >> 5;
        const float* __restrict__ W = a.wsrc[z];
        unsigned short* __restrict__ WT = a.wdst[z];
        const int tx = tid & 31;
        const int ty = tid >> 5;          // 0..7
        const int nb = bx << 5;
        const int kb = by << 5;
#pragma unroll
        for (int i = 0; i < 4; ++i)
            tbuf[ty + (i << 3)][tx] =
                f2bf(W[(size_t)(kb + ty + (i << 3)) * D_MODEL + nb + tx]);
        __syncthreads();
#pragma unroll
        for (int i = 0; i < 4; ++i)
            WT[(size_t)(nb + ty + (i << 3)) * D_MODEL + kb + tx] =
                tbuf[tx][ty + (i << 3)];
    } else {
        // mask pack, swapped-QK layout (bit(lane) for word (r,n) of (bb,qw,t64))
        const int bxm = id - 4096;
        const int lane = tid & 63;
        const int l15  = lane & 15;
        const int kg   = lane >> 4;
        const int wv   = (bxm << 2) + (tid >> 6);   // 0..8191
        const int t    = wv & 31;
        const int qw   = (wv >> 5) & 127;
        const int bb   = wv >> 12;

        const int* mb = a.mask + (size_t)bb * SEQ * SEQ
                      + (size_t)((qw << 4) + l15) * SEQ + (t << 6) + (kg << 2);
        unsigned long long* wout = a.wm + ((((size_t)bb * 128 + qw) * 32 + t) << 4);

        int4 ln[4];
#pragma unroll
        for (int n = 0; n < 4; ++n)
            ln[n] = *reinterpret_cast<const int4*>(mb + (n << 4));
#pragma unroll
        for (int r = 0; r < 4; ++r)
#pragma unroll
            for (int n = 0; n < 4; ++n) {
                const int mvv = (&ln[n].x)[r];
                const unsigned long long bal = __ballot(mvv != 0);
                if (lane == 0) wout[(r << 2) | n] = bal;
            }
    }
}

// ---------------------------------------------------------------------------
// MFMA GEMM. Fragment/LDS layouts identical to the verified m97 structure.
// AF32=true (QKV): A read as fp32 from global, reg-staged with cvt_pk->bf16
//   during the LDS write (flash-proven prefetch pattern), As/Bs double-
//   buffered -> ONE barrier per K-step. B stays global_load_lds.
// AF32=false (O-proj): R7-verified single-buffer 2-barrier path, MI=2.
// ---------------------------------------------------------------------------
template <typename OutT> struct GArgs {
    const float*          Xf[3];   // AF32 path (fp32 A)
    const unsigned short* X[3];    // bf16 A path
    const unsigned short* W[3];
    const float*          Bi[3];
    OutT*                 O[3];
    float                 scl[3];
};

__device__ __forceinline__ void st_out(float* p, float v) { *p = v; }
__device__ __forceinline__ void st_out(unsigned short* p, float v) { *p = f2bf(v); }

template <typename OutT, int MI, bool AF32>
__global__ __launch_bounds__(256)
void gemm_bf16(const GArgs<OutT> args, const int head_split)
{
    constexpr int NB = AF32 ? 2 : 1;
    __shared__ __align__(16) unsigned short As[NB][MI * 32][32];
    __shared__ __align__(16) unsigned short Bs[NB][128][32];

    const int opz = blockIdx.z;
    const unsigned short* __restrict__ WT = args.W[opz];
    const float* __restrict__ bias        = args.Bi[opz];
    OutT* __restrict__ out                = args.O[opz];
    const float scl                       = args.scl[opz];

    const int tid = threadIdx.x;
    const int wid = tid >> 6;
    const int wy  = wid >> 1;
    const int wx  = wid & 1;
    const int l15 = tid & 15;
    const int kg  = (tid >> 4) & 3;

    // XCD-aware swizzle: same-XCD blocks (id%8) get consecutive tile chunks.
    const int nwgy = (int)gridDim.y;                          // m-tiles per plane
    const int id = ((int)blockIdx.y << 3) | (int)blockIdx.x;
    const int sw = (id & 7) * nwgy + (id >> 3);
    const int n0 = (sw & 7) << 7;
    const int m0 = (sw >> 3) * (MI * 32);

    const int lane = tid & 63;
    const int gr   = lane >> 2;         // 0..15 row within 16-row chunk
    const int gc   = (lane & 3) << 3;   // 0,8,16,24 shorts (16 B)

    f32x4 acc[MI][4];
#pragma unroll
    for (int i = 0; i < MI; ++i)
#pragma unroll
        for (int j = 0; j < 4; ++j)
            acc[i][j] = (f32x4){0.f, 0.f, 0.f, 0.f};

    if constexpr (AF32) {
        const float* __restrict__ Xf = args.Xf[opz];
        // A reg-staging ids: thread -> row tid>>1, 16-float k-half (tid&1)
        const int arow  = tid >> 1;
        const int acol  = (tid & 1) << 4;   // k offset (floats == shorts)

        // prologue: A regs for t=0; async B tile 0 -> Bs[0]
        float4 ar[4];
        {
            const float* asrc = &Xf[(size_t)(m0 + arow) * D_MODEL + acol];
#pragma unroll
            for (int i = 0; i < 4; ++i)
                ar[i] = *reinterpret_cast<const float4*>(asrc + (i << 2));
        }
#pragma unroll
        for (int cc = 0; cc < 2; ++cc) {
            const int cch = (wid << 1) + cc;
            async_copy16(&WT[(size_t)(n0 + (cch << 4) + gr) * D_MODEL + gc],
                         &Bs[0][cch << 4][0]);
        }

#pragma unroll 1
        for (int t = 0; t < D_MODEL / 32; ++t) {
            const int c = t & 1;

            // cvt fp32 regs -> bf16, write to As[c] (proven [128][32] layout)
            unsigned pw[8];
#pragma unroll
            for (int i = 0; i < 4; ++i) {
                __asm__("v_cvt_pk_bf16_f32 %0, %1, %2"
                        : "=v"(pw[2 * i]) : "v"(ar[i].x), "v"(ar[i].y));
                __asm__("v_cvt_pk_bf16_f32 %0, %1, %2"
                        : "=v"(pw[2 * i + 1]) : "v"(ar[i].z), "v"(ar[i].w));
            }
            union { unsigned u[4]; uint4 v; } q0, q1;
            q0.u[0] = pw[0]; q0.u[1] = pw[1]; q0.u[2] = pw[2]; q0.u[3] = pw[3];
            q1.u[0] = pw[4]; q1.u[1] = pw[5]; q1.u[2] = pw[6]; q1.u[3] = pw[7];
            *reinterpret_cast<uint4*>(&As[c][arow][acol])     = q0.v;
            *reinterpret_cast<uint4*>(&As[c][arow][acol + 8]) = q1.v;

            __syncthreads();   // buffer c complete (writes + async B drained)

            // prefetch t+1: A regs + async B -> buffers c^1
            if (t + 1 < D_MODEL / 32) {
                const int k0n = (t + 1) << 5;
                const float* asrc = &Xf[(size_t)(m0 + arow) * D_MODEL + k0n + acol];
#pragma unroll
                for (int i = 0; i < 4; ++i)
                    ar[i] = *reinterpret_cast<const float4*>(asrc + (i << 2));
#pragma unroll
                for (int cc = 0; cc < 2; ++cc) {
                    const int cch = (wid << 1) + cc;
                    async_copy16(&WT[(size_t)(n0 + (cch << 4) + gr) * D_MODEL + k0n + gc],
                                 &Bs[c ^ 1][cch << 4][0]);
                }
            }

            bf16x8 a[MI], b[4];
#pragma unroll
            for (int i = 0; i < MI; ++i)
                a[i] = *reinterpret_cast<const bf16x8*>(
                    &As[c][(wy * MI + i) * 16 + l15][kg << 3]);
#pragma unroll
            for (int j = 0; j < 4; ++j)
                b[j] = *reinterpret_cast<const bf16x8*>(
                    &Bs[c][(wx << 6) + (j << 4) + l15][kg << 3]);
#pragma unroll
            for (int i = 0; i < MI; ++i)
#pragma unroll
                for (int j = 0; j < 4; ++j)
                    acc[i][j] = __builtin_amdgcn_mfma_f32_16x16x32_bf16(
                        a[i], b[j], acc[i][j], 0, 0, 0);
        }
    } else {
        const unsigned short* __restrict__ X = args.X[opz];
#pragma unroll 1
        for (int t = 0; t < D_MODEL / 32; ++t) {
            const int k0 = t << 5;

            __syncthreads();   // (A) prior iter's frag reads complete
#pragma unroll
            for (int cc = 0; cc < 2; ++cc) {
                const int c = (wid << 1) + cc;     // 16-row chunk id, 0..7
                async_copy16(&WT[(size_t)(n0 + (c << 4) + gr) * D_MODEL + k0 + gc],
                             &Bs[0][c << 4][0]);
                if (MI == 4)
                    async_copy16(&X[(size_t)(m0 + (c << 4) + gr) * D_MODEL + k0 + gc],
                                 &As[0][c << 4][0]);
            }
            if (MI == 2)   // only 4 A-chunks: one per wave
                async_copy16(&X[(size_t)(m0 + (wid << 4) + gr) * D_MODEL + k0 + gc],
                             &As[0][wid << 4][0]);
            __syncthreads();   // (B) DMA drained (vmcnt0) + visible

            bf16x8 a[MI], b[4];
#pragma unroll
            for (int i = 0; i < MI; ++i)
                a[i] = *reinterpret_cast<const bf16x8*>(
                    &As[0][(wy * MI + i) * 16 + l15][kg << 3]);
#pragma unroll
            for (int j = 0; j < 4; ++j)
                b[j] = *reinterpret_cast<const bf16x8*>(
                    &Bs[0][(wx << 6) + (j << 4) + l15][kg << 3]);
#pragma unroll
            for (int i = 0; i < MI; ++i)
#pragma unroll
                for (int j = 0; j < 4; ++j)
                    acc[i][j] = __builtin_amdgcn_mfma_f32_16x16x32_bf16(
                        a[i], b[j], acc[i][j], 0, 0, 0);
        }
    }

    float bv[4];
#pragma unroll
    for (int j = 0; j < 4; ++j)
        bv[j] = bias[n0 + (wx << 6) + (j << 4) + l15];

#pragma unroll
    for (int i = 0; i < MI; ++i) {
#pragma unroll
        for (int r = 0; r < 4; ++r) {
            const int m = m0 + (wy * MI + i) * 16 + (kg << 2) + r;
#pragma unroll
            for (int j = 0; j < 4; ++j) {
                const int n = n0 + (wx << 6) + (j << 4) + l15;
                const float val = (acc[i][j][r] + bv[j]) * scl;
                if (head_split) {
                    const int bbx = m >> 11;
                    const int ss  = m & (SEQ - 1);
                    const int hhx = n >> 6;
                    const int dd  = n & (DK - 1);
                    st_out(&out[((size_t)(bbx * NHEADS + hhx) * SEQ + ss) * DK + dd], val);
                } else {
                    st_out(&out[(size_t)m * D_MODEL + n], val);
                }
            }
        }
    }
}

// ---------------------------------------------------------------------------
// MFMA flash attention — unchanged from R8 (swapped QK^T, in-register P,
// two Q-tiles/wave, KVBLK=128, MFMA ones-trick row sums).
// ---------------------------------------------------------------------------
__global__ __launch_bounds__(256)
void flash_mfma(const unsigned short* __restrict__ Qb,
                const unsigned short* __restrict__ Kb,
                const unsigned short* __restrict__ Vb,
                const unsigned long long* __restrict__ wmask,
                unsigned short* __restrict__ ctx)
{
    __shared__ __align__(16) unsigned short Kbf[2][128][72];
    __shared__ __align__(16) unsigned short V3 [2][64][136];

    const int tid  = threadIdx.x;
    const int w    = tid >> 6;
    const int lane = tid & 63;
    const int l15  = lane & 15;
    const int kg   = lane >> 4;

    // XCD swizzle over the 512-block grid (512 % 8 == 0 -> bijective).
    const int flat = ((int)blockIdx.z * NHEADS + (int)blockIdx.y) * (SEQ / 128)
                   + (int)blockIdx.x;
    const int swz  = ((flat & 7) << 6) | (flat >> 3);
    const int q0 = (swz & 15) << 7;         // 0..1920, step 128
    const int hh = (swz >> 4) & 15;
    const int bb = swz >> 8;

    const unsigned short* Qh = Qb + (size_t)(bb * NHEADS + hh) * SEQ * DK;
    const unsigned short* Kh = Kb + (size_t)(bb * NHEADS + hh) * SEQ * DK;
    const unsigned short* Vh = Vb + (size_t)(bb * NHEADS + hh) * SEQ * DK;

    bf16x8 aq[2][2];   // [qi][half]: lane holds Q[q=l15][d=8kg+j]
#pragma unroll
    for (int qi = 0; qi < 2; ++qi) {
        const unsigned short* qrow =
            Qh + (size_t)(q0 + w * 32 + qi * 16 + l15) * DK + (kg << 3);
        aq[qi][0] = *reinterpret_cast<const bf16x8*>(qrow);
        aq[qi][1] = *reinterpret_cast<const bf16x8*>(qrow + 32);
    }

    const int krow = tid >> 2;            // 0..63 (this thread: rows krow, krow+64)
    const int kcb  = (tid & 3) << 4;      // bf16 offset 0,16,32,48
    const int vkb  = (tid & 15) << 2;     // V k base within a 64-half
    const int vdb  = (tid >> 4) << 2;     // V d base (4 consecutive d)
    const int q16  = tid & 15;            // k-quad id within half
    const int voff = ((q16 & 3) << 5) | ((q16 >> 2) << 2);  // half 0; half1 = +16

    // wave-uniform bases into the packed mask array (qw = q0/16 + 2w + qi)
    const int wbase0 = __builtin_amdgcn_readfirstlane(
        (bb * 128 + (q0 >> 4) + (w << 1)) << 9);
    const int wbase1 = wbase0 + 512;

    // all-ones bf16 B-fragment for the rowsum MFMA
    union { unsigned u[4]; bf16x8 v; } onesu;
#pragma unroll
    for (int j = 0; j < 4; ++j) onesu.u[j] = 0x3F803F80u;
    const bf16x8 onesv = onesu.v;

    f32x4 Lacc[2];
    f32x4 O4[2][4];
#pragma unroll
    for (int qi = 0; qi < 2; ++qi) {
        Lacc[qi] = (f32x4){0.f, 0.f, 0.f, 0.f};
#pragma unroll
        for (int db = 0; db < 4; ++db) O4[qi][db] = (f32x4){0.f, 0.f, 0.f, 0.f};
    }

    // prologue: prefetch 128-row tile 0 into registers
    uint4 kv0a = *reinterpret_cast<const uint4*>(Kh + (size_t)krow * DK + kcb);
    uint4 kv1a = *reinterpret_cast<const uint4*>(Kh + (size_t)krow * DK + kcb + 8);
    uint4 kv0b = *reinterpret_cast<const uint4*>(Kh + (size_t)(krow + 64) * DK + kcb);
    uint4 kv1b = *reinterpret_cast<const uint4*>(Kh + (size_t)(krow + 64) * DK + kcb + 8);
    uint2 vra[4], vrb[4];
#pragma unroll
    for (int i = 0; i < 4; ++i) {
        vra[i] = *reinterpret_cast<const uint2*>(Vh + (size_t)(vkb + i) * DK + vdb);
        vrb[i] = *reinterpret_cast<const uint2*>(Vh + (size_t)(64 + vkb + i) * DK + vdb);
    }

#pragma unroll 1
    for (int t = 0; t < NT128; ++t) {
        const int c = t & 1;

        // ---- stage 128-row tile t into buffer c ----
        *reinterpret_cast<uint4*>(&Kbf[c][krow][kcb])          = kv0a;
        *reinterpret_cast<uint4*>(&Kbf[c][krow][kcb + 8])      = kv1a;
        *reinterpret_cast<uint4*>(&Kbf[c][krow + 64][kcb])     = kv0b;
        *reinterpret_cast<uint4*>(&Kbf[c][krow + 64][kcb + 8]) = kv1b;
#pragma unroll
        for (int hf = 0; hf < 2; ++hf) {   // transpose each 64-k half
            const uint2* vr = hf ? vrb : vra;
            const int vo = voff + (hf << 4);
            uint2 o;
            o.x = (vr[0].x & 0xFFFFu) | (vr[1].x << 16);
            o.y = (vr[2].x & 0xFFFFu) | (vr[3].x << 16);
            *reinterpret_cast<uint2*>(&V3[c][vdb + 0][vo]) = o;
            o.x = (vr[0].x >> 16) | (vr[1].x & 0xFFFF0000u);
            o.y = (vr[2].x >> 16) | (vr[3].x & 0xFFFF0000u);
            *reinterpret_cast<uint2*>(&V3[c][vdb + 1][vo]) = o;
            o.x = (vr[0].y & 0xFFFFu) | (vr[1].y << 16);
            o.y = (vr[2].y & 0xFFFFu) | (vr[3].y << 16);
            *reinterpret_cast<uint2*>(&V3[c][vdb + 2][vo]) = o;
            o.x = (vr[0].y >> 16) | (vr[1].y & 0xFFFF0000u);
            o.y = (vr[2].y >> 16) | (vr[3].y & 0xFFFF0000u);
            *reinterpret_cast<uint2*>(&V3[c][vdb + 3][vo]) = o;
        }
        __syncthreads();   // buffer c visible (other buffer free for writes)

        // ---- prefetch NEXT 128-tile (latency hides under this compute) ----
        if (t + 1 < NT128) {
            const int kn = (t + 1) << 7;
            kv0a = *reinterpret_cast<const uint4*>(Kh + (size_t)(kn + krow) * DK + kcb);
            kv1a = *reinterpret_cast<const uint4*>(Kh + (size_t)(kn + krow) * DK + kcb + 8);
            kv0b = *reinterpret_cast<const uint4*>(Kh + (size_t)(kn + krow + 64) * DK + kcb);
            kv1b = *reinterpret_cast<const uint4*>(Kh + (size_t)(kn + krow + 64) * DK + kcb + 8);
#pragma unroll
            for (int i = 0; i < 4; ++i) {
                vra[i] = *reinterpret_cast<const uint2*>(
                    Vh + (size_t)(kn + vkb + i) * DK + vdb);
                vrb[i] = *reinterpret_cast<const uint2*>(
                    Vh + (size_t)(kn + 64 + vkb + i) * DK + vdb);
            }
        }

        // ---- two 64-k subtiles, layouts identical to the verified kernel ----
#pragma unroll
        for (int h = 0; h < 2; ++h) {
            // QK^T both q-tiles, K-fragments read once
            f32x4 S[2][4];
#pragma unroll
            for (int n = 0; n < 4; ++n) {
                const bf16x8 b0 = *reinterpret_cast<const bf16x8*>(
                    &Kbf[c][(h << 6) + 16 * n + l15][kg << 3]);
                const bf16x8 b1 = *reinterpret_cast<const bf16x8*>(
                    &Kbf[c][(h << 6) + 16 * n + l15][(kg << 3) + 32]);
#pragma unroll
                for (int qi = 0; qi < 2; ++qi) {
                    f32x4 acc = (f32x4){0.f, 0.f, 0.f, 0.f};
                    acc = __builtin_amdgcn_mfma_f32_16x16x32_bf16(b0, aq[qi][0], acc, 0, 0, 0);
                    acc = __builtin_amdgcn_mfma_f32_16x16x32_bf16(b1, aq[qi][1], acc, 0, 0, 0);
                    S[qi][n] = acc;
                }
            }

            // softmax per q-tile: P = mask ? exp2(S) : 0 (Q pre-scaled)
            bf16x8 paf[2][2];
#pragma unroll
            for (int qi = 0; qi < 2; ++qi) {
                const unsigned long long* wmt =
                    wmask + (qi ? wbase1 : wbase0) + (((t << 1) | h) << 4);
                unsigned long long wmv[16];
#pragma unroll
                for (int rn = 0; rn < 16; ++rn) wmv[rn] = wmt[rn];

                unsigned pw01[4], pw23[4];
#pragma unroll
                for (int n = 0; n < 4; ++n) {
                    float xv[4];
#pragma unroll
                    for (int r = 0; r < 4; ++r) {
                        float e;
                        __asm__("v_exp_f32 %0, %1" : "=v"(e) : "v"(S[qi][n][r]));
                        __asm__("v_cndmask_b32 %0, 0, %1, %2"
                                : "=v"(e) : "v"(e), "s"(wmv[(r << 2) | n]));
                        xv[r] = e;
                    }
                    __asm__("v_cvt_pk_bf16_f32 %0, %1, %2"
                            : "=v"(pw01[n]) : "v"(xv[0]), "v"(xv[1]));
                    __asm__("v_cvt_pk_bf16_f32 %0, %1, %2"
                            : "=v"(pw23[n]) : "v"(xv[2]), "v"(xv[3]));
                }
                union { unsigned u[4]; bf16x8 v; } pa0, pa1;
                pa0.u[0] = pw01[0]; pa0.u[1] = pw23[0]; pa0.u[2] = pw01[1]; pa0.u[3] = pw23[1];
                pa1.u[0] = pw01[2]; pa1.u[1] = pw23[2]; pa1.u[2] = pw01[3]; pa1.u[3] = pw23[3];
                paf[qi][0] = pa0.v;
                paf[qi][1] = pa1.v;

                // rowsum via MFMA: Lacc[r] = sum over this subtile's 64 k
                Lacc[qi] = __builtin_amdgcn_mfma_f32_16x16x32_bf16(
                    paf[qi][0], onesv, Lacc[qi], 0, 0, 0);
                Lacc[qi] = __builtin_amdgcn_mfma_f32_16x16x32_bf16(
                    paf[qi][1], onesv, Lacc[qi], 0, 0, 0);
            }

            // PV both q-tiles, V-fragments read once
#pragma unroll
            for (int db = 0; db < 4; ++db) {
                const unsigned short* vbase =
                    &V3[c][(db << 4) + l15][(kg << 5) | (h << 4)];
                const bf16x8 v0 = *reinterpret_cast<const bf16x8*>(vbase);
                const bf16x8 v1 = *reinterpret_cast<const bf16x8*>(vbase + 8);
#pragma unroll
                for (int qi = 0; qi < 2; ++qi) {
                    O4[qi][db] = __builtin_amdgcn_mfma_f32_16x16x32_bf16(
                        paf[qi][0], v0, O4[qi][db], 0, 0, 0);
                    O4[qi][db] = __builtin_amdgcn_mfma_f32_16x16x32_bf16(
                        paf[qi][1], v1, O4[qi][db], 0, 0, 0);
                }
            }
        }
    }

    // epilogue: Lacc[qi][r] holds the full row sum for q = 4kg+r (replicated
    // across l15) — normalize and store, no shuffles needed.
#pragma unroll
    for (int qi = 0; qi < 2; ++qi) {
#pragma unroll
        for (int r = 0; r < 4; ++r) {
            const float inv = 1.f / Lacc[qi][r];
            const size_t base =
                (size_t)(bb * SEQ + q0 + w * 32 + qi * 16 + (kg << 2) + r) * D_MODEL
                + hh * DK + l15;
#pragma unroll
            for (int db = 0; db < 4; ++db)
                ctx[base + 16 * db] = f2bf(O4[qi][db][r] * inv);
        }
    }
}

// ---------------------------------------------------------------------------
extern "C" void kernel_launch(void* const* d_in, const int* in_sizes, int n_in,
                              void* d_out, int out_size, void* d_ws, size_t ws_size,
                              hipStream_t stream)
{
    const float* query = (const float*)d_in[0];
    const float* key   = (const float*)d_in[1];
    const float* value = (const float*)d_in[2];
    const int*   mask  = (const int*)d_in[3];
    const float* Wq = (const float*)d_in[4];
    const float* bq = (const float*)d_in[5];
    const float* Wk = (const float*)d_in[6];
    const float* bk = (const float*)d_in[7];
    const float* Wv = (const float*)d_in[8];
    const float* bv = (const float*)d_in[9];
    const float* Wo = (const float*)d_in[10];
    const float* bo = (const float*)d_in[11];

    unsigned short* ws = (unsigned short*)d_ws;
    const size_t TE = (size_t)M_TOTAL * D_MODEL;     // 4,194,304
    const size_t WE = (size_t)D_MODEL * D_MODEL;     // 1,048,576
    unsigned short* WTq = ws;
    unsigned short* WTk = WTq + WE;
    unsigned short* WTv = WTk + WE;
    unsigned short* WTo = WTv + WE;
    unsigned short* Qb  = WTo + WE;
    unsigned short* Kb  = Qb + TE;
    unsigned short* Vb  = Kb + TE;
    unsigned short* Ctx = Vb + TE;                   // ends at 40 MB
    unsigned long long* WM = (unsigned long long*)(Ctx + TE);  // +1 MB packed masks

    PrepArgs pa;
    pa.wsrc[0] = Wq;  pa.wsrc[1] = Wk;  pa.wsrc[2] = Wv;  pa.wsrc[3] = Wo;
    pa.wdst[0] = WTq; pa.wdst[1] = WTk; pa.wdst[2] = WTv; pa.wdst[3] = WTo;
    pa.mask = mask; pa.wm = WM;
    prep_all<<<dim3(6144, 1, 1), 256, 0, stream>>>(pa);

    GArgs<unsigned short> qkv;
    qkv.Xf[0] = query; qkv.Xf[1] = key; qkv.Xf[2] = value;
    qkv.X[0] = nullptr; qkv.X[1] = nullptr; qkv.X[2] = nullptr;
    qkv.W[0] = WTq; qkv.W[1] = WTk; qkv.W[2] = WTv;
    qkv.Bi[0] = bq; qkv.Bi[1] = bk; qkv.Bi[2] = bv;
    qkv.O[0] = Qb;  qkv.O[1] = Kb;  qkv.O[2] = Vb;
    qkv.scl[0] = QSCALE; qkv.scl[1] = 1.f; qkv.scl[2] = 1.f;
    gemm_bf16<unsigned short, 4, true><<<dim3(8, 32, 3), 256, 0, stream>>>(qkv, 1);

    flash_mfma<<<dim3(SEQ / 128, NHEADS, BATCH), 256, 0, stream>>>(
        Qb, Kb, Vb, WM, Ctx);

    GArgs<float> op;
    op.Xf[0] = nullptr; op.Xf[1] = nullptr; op.Xf[2] = nullptr;
    op.X[0] = Ctx;  op.X[1] = Ctx;  op.X[2] = Ctx;
    op.W[0] = WTo;  op.W[1] = WTo;  op.W[2] = WTo;
    op.Bi[0] = bo;  op.Bi[1] = bo;  op.Bi[2] = bo;
    op.O[0] = (float*)d_out; op.O[1] = (float*)d_out; op.O[2] = (float*)d_out;
    op.scl[0] = 1.f; op.scl[1] = 1.f; op.scl[2] = 1.f;
    // 64x128 tiles: 8x64 = 512 blocks = 2 blocks/CU
    gemm_bf16<float, 2, false><<<dim3(8, 64, 1), 256, 0, stream>>>(op, 0);
}

// Round 12
// 261.094 us; speedup vs baseline: 1.0803x; 1.0803x over previous
//
#include <hip/hip_runtime.h>
#include <math.h>

#define D_MODEL 1024
#define NHEADS  16
#define DK      64
#define BATCH   2
#define SEQ     2048
#define M_TOTAL (BATCH * SEQ)   // 4096
#define NT128   (SEQ / 128)     // 16 k-tiles of 128
// Q is PRE-SCALED by 0.125*log2e in the QKV GEMM epilogue, so flash softmax
// is P = mask ? exp2(S) : 0 (shift-invariant; S <= 12*log2e -> exp2 <= 1.7e5).
#define QSCALE 0.18033688011112042f

typedef __attribute__((ext_vector_type(8))) short bf16x8;  // 8 bf16 (4 VGPRs)
typedef __attribute__((ext_vector_type(4))) float f32x4;   // MFMA C/D

// ---- fp32 -> bf16 (RNE) ----------------------------------------------------
__device__ __forceinline__ unsigned short f2bf(float f) {
    union { float f; unsigned int i; } v; v.f = f;
    return (unsigned short)((v.i + 0x7FFFu + ((v.i >> 16) & 1u)) >> 16);
}

// ---- async global->LDS, 16 B per lane (dest = wave-uniform base + lane*16) --
__device__ __forceinline__ void async_copy16(const void* g, void* l) {
    __builtin_amdgcn_global_load_lds(
        (const __attribute__((address_space(1))) unsigned int*)g,
        (__attribute__((address_space(3))) unsigned int*)l, 16, 0, 0);
}

// ---------------------------------------------------------------------------
// prep_all (R7-verified): ONE dispatch for all three prep ops.
//   blocks [0,12288):      flat fp32->bf16 of query/key/value (4096 per z)
//   blocks [12288,16384):  W [k][n] fp32 -> WT [n][k] bf16 (1024 per z, 4 z)
//   blocks [16384,18432):  mask -> packed 64-bit lane masks (swapped-QK layout)
// ---------------------------------------------------------------------------
struct PrepArgs {
    const float* xs[3]; unsigned short* xd[3];      // q/k/v flat cvt
    const float* wsrc[4]; unsigned short* wdst[4];  // Wq/Wk/Wv/Wo transpose cvt
    const int* mask; unsigned long long* wm;        // mask pack
};

__global__ __launch_bounds__(256)
void prep_all(const PrepArgs a)
{
    __shared__ unsigned short tbuf[32][33];
    const int id  = blockIdx.x;
    const int tid = threadIdx.x;

    if (id < 12288) {
        const int z = id >> 12;
        const int x = id & 4095;
        const float* __restrict__ s = a.xs[z];
        unsigned short* __restrict__ d = a.xd[z];
        const size_t i = ((size_t)x * 256 + tid) * 4;
        const float4 v = *reinterpret_cast<const float4*>(&s[i]);
        ushort4 o;
        o.x = f2bf(v.x); o.y = f2bf(v.y); o.z = f2bf(v.z); o.w = f2bf(v.w);
        *reinterpret_cast<ushort4*>(&d[i]) = o;
    } else if (id < 16384) {
        const int r  = id - 12288;
        const int z  = r >> 10;
        const int rem = r & 1023;
        const int bx = rem & 31;
        const int by = rem >> 5;
        const float* __restrict__ W = a.wsrc[z];
        unsigned short* __restrict__ WT = a.wdst[z];
        const int tx = tid & 31;
        const int ty = tid >> 5;          // 0..7
        const int nb = bx << 5;
        const int kb = by << 5;
#pragma unroll
        for (int i = 0; i < 4; ++i)
            tbuf[ty + (i << 3)][tx] =
                f2bf(W[(size_t)(kb + ty + (i << 3)) * D_MODEL + nb + tx]);
        __syncthreads();
#pragma unroll
        for (int i = 0; i < 4; ++i)
            WT[(size_t)(nb + ty + (i << 3)) * D_MODEL + kb + tx] =
                tbuf[tx][ty + (i << 3)];
    } else {
        // mask pack, swapped-QK layout (bit(lane) for word (r,n) of (bb,qw,t64))
        const int bxm = id - 16384;
        const int lane = tid & 63;
        const int l15  = lane & 15;
        const int kg   = lane >> 4;
        const int wv   = (bxm << 2) + (tid >> 6);   // 0..8191
        const int t    = wv & 31;
        const int qw   = (wv >> 5) & 127;
        const int bb   = wv >> 12;

        const int* mb = a.mask + (size_t)bb * SEQ * SEQ
                      + (size_t)((qw << 4) + l15) * SEQ + (t << 6) + (kg << 2);
        unsigned long long* wout = a.wm + ((((size_t)bb * 128 + qw) * 32 + t) << 4);

        int4 ln[4];
#pragma unroll
        for (int n = 0; n < 4; ++n)
            ln[n] = *reinterpret_cast<const int4*>(mb + (n << 4));
#pragma unroll
        for (int r = 0; r < 4; ++r)
#pragma unroll
            for (int n = 0; n < 4; ++n) {
                const int mvv = (&ln[n].x)[r];
                const unsigned long long bal = __ballot(mvv != 0);
                if (lane == 0) wout[(r << 2) | n] = bal;
            }
    }
}

// ---------------------------------------------------------------------------
// MFMA GEMM (R7-verified m97 structure).
// Templated m-tile: MI = A-frags per wave. Block tile = (MI*32) x 128, BK=32,
// 256 thr = 4 waves (2x2). MI=4 -> 128x128 (QKV). MI=2 -> 64x128 (O-proj,
// 512 blocks = 2 blocks/CU). XCD-chunked swizzle (chunk = gridDim.y).
// ---------------------------------------------------------------------------
template <typename OutT> struct GArgs {
    const unsigned short* X[3];
    const unsigned short* W[3];
    const float*          Bi[3];
    OutT*                 O[3];
    float                 scl[3];
};

__device__ __forceinline__ void st_out(float* p, float v) { *p = v; }
__device__ __forceinline__ void st_out(unsigned short* p, float v) { *p = f2bf(v); }

template <typename OutT, int MI>
__global__ __launch_bounds__(256)
void gemm_bf16(const GArgs<OutT> args, const int head_split)
{
    __shared__ __align__(16) unsigned short As[MI * 32][32];
    __shared__ __align__(16) unsigned short Bs[128][32];

    const int opz = blockIdx.z;
    const unsigned short* __restrict__ X  = args.X[opz];
    const unsigned short* __restrict__ WT = args.W[opz];
    const float* __restrict__ bias        = args.Bi[opz];
    OutT* __restrict__ out                = args.O[opz];
    const float scl                       = args.scl[opz];

    const int tid = threadIdx.x;
    const int wid = tid >> 6;
    const int wy  = wid >> 1;
    const int wx  = wid & 1;
    const int l15 = tid & 15;
    const int kg  = (tid >> 4) & 3;

    // XCD-aware swizzle: same-XCD blocks (id%8) get consecutive tile chunks.
    const int nwgy = (int)gridDim.y;                          // m-tiles per plane
    const int id = ((int)blockIdx.y << 3) | (int)blockIdx.x;
    const int sw = (id & 7) * nwgy + (id >> 3);
    const int n0 = (sw & 7) << 7;
    const int m0 = (sw >> 3) * (MI * 32);

    const int lane = tid & 63;
    const int gr   = lane >> 2;         // 0..15 row within 16-row chunk
    const int gc   = (lane & 3) << 3;   // 0,8,16,24 shorts (16 B)

    f32x4 acc[MI][4];
#pragma unroll
    for (int i = 0; i < MI; ++i)
#pragma unroll
        for (int j = 0; j < 4; ++j)
            acc[i][j] = (f32x4){0.f, 0.f, 0.f, 0.f};

#pragma unroll 1
    for (int t = 0; t < D_MODEL / 32; ++t) {
        const int k0 = t << 5;

        __syncthreads();   // (A) prior iter's frag reads complete
#pragma unroll
        for (int cc = 0; cc < 2; ++cc) {
            const int c = (wid << 1) + cc;     // 16-row chunk id, 0..7
            async_copy16(&WT[(size_t)(n0 + (c << 4) + gr) * D_MODEL + k0 + gc],
                         &Bs[c << 4][0]);
            if (MI == 4)
                async_copy16(&X[(size_t)(m0 + (c << 4) + gr) * D_MODEL + k0 + gc],
                             &As[c << 4][0]);
        }
        if (MI == 2)   // only 4 A-chunks: one per wave
            async_copy16(&X[(size_t)(m0 + (wid << 4) + gr) * D_MODEL + k0 + gc],
                         &As[wid << 4][0]);
        __syncthreads();   // (B) DMA drained (vmcnt0) + visible

        bf16x8 a[MI], b[4];
#pragma unroll
        for (int i = 0; i < MI; ++i)
            a[i] = *reinterpret_cast<const bf16x8*>(
                &As[(wy * MI + i) * 16 + l15][kg << 3]);
#pragma unroll
        for (int j = 0; j < 4; ++j)
            b[j] = *reinterpret_cast<const bf16x8*>(
                &Bs[(wx << 6) + (j << 4) + l15][kg << 3]);
#pragma unroll
        for (int i = 0; i < MI; ++i)
#pragma unroll
            for (int j = 0; j < 4; ++j)
                acc[i][j] = __builtin_amdgcn_mfma_f32_16x16x32_bf16(
                    a[i], b[j], acc[i][j], 0, 0, 0);
    }

    float bv[4];
#pragma unroll
    for (int j = 0; j < 4; ++j)
        bv[j] = bias[n0 + (wx << 6) + (j << 4) + l15];

#pragma unroll
    for (int i = 0; i < MI; ++i) {
#pragma unroll
        for (int r = 0; r < 4; ++r) {
            const int m = m0 + (wy * MI + i) * 16 + (kg << 2) + r;
#pragma unroll
            for (int j = 0; j < 4; ++j) {
                const int n = n0 + (wx << 6) + (j << 4) + l15;
                const float val = (acc[i][j][r] + bv[j]) * scl;
                if (head_split) {
                    const int bbx = m >> 11;
                    const int ss  = m & (SEQ - 1);
                    const int hhx = n >> 6;
                    const int dd  = n & (DK - 1);
                    st_out(&out[((size_t)(bbx * NHEADS + hhx) * SEQ + ss) * DK + dd], val);
                } else {
                    st_out(&out[(size_t)m * D_MODEL + n], val);
                }
            }
        }
    }
}

// ---------------------------------------------------------------------------
// MFMA flash attention (R8-verified): swapped QK^T + in-register P, two
// Q-tiles per wave, KVBLK=128 (two verified 64-k subtiles per staging
// barrier), MFMA ones-trick row sums (no VALU adds, no epilogue shuffles).
// The R10/R11 in-block K-split showed nondeterministic failures (race) and
// is abandoned; this kernel is byte-identical to the R8 passing run.
// ---------------------------------------------------------------------------
__global__ __launch_bounds__(256)
void flash_mfma(const unsigned short* __restrict__ Qb,
                const unsigned short* __restrict__ Kb,
                const unsigned short* __restrict__ Vb,
                const unsigned long long* __restrict__ wmask,
                unsigned short* __restrict__ ctx)
{
    __shared__ __align__(16) unsigned short Kbf[2][128][72];
    __shared__ __align__(16) unsigned short V3 [2][64][136];

    const int tid  = threadIdx.x;
    const int w    = tid >> 6;
    const int lane = tid & 63;
    const int l15  = lane & 15;
    const int kg   = lane >> 4;

    // XCD swizzle over the 512-block grid (512 % 8 == 0 -> bijective).
    const int flat = ((int)blockIdx.z * NHEADS + (int)blockIdx.y) * (SEQ / 128)
                   + (int)blockIdx.x;
    const int swz  = ((flat & 7) << 6) | (flat >> 3);
    const int q0 = (swz & 15) << 7;         // 0..1920, step 128
    const int hh = (swz >> 4) & 15;
    const int bb = swz >> 8;

    const unsigned short* Qh = Qb + (size_t)(bb * NHEADS + hh) * SEQ * DK;
    const unsigned short* Kh = Kb + (size_t)(bb * NHEADS + hh) * SEQ * DK;
    const unsigned short* Vh = Vb + (size_t)(bb * NHEADS + hh) * SEQ * DK;

    bf16x8 aq[2][2];   // [qi][half]: lane holds Q[q=l15][d=8kg+j]
#pragma unroll
    for (int qi = 0; qi < 2; ++qi) {
        const unsigned short* qrow =
            Qh + (size_t)(q0 + w * 32 + qi * 16 + l15) * DK + (kg << 3);
        aq[qi][0] = *reinterpret_cast<const bf16x8*>(qrow);
        aq[qi][1] = *reinterpret_cast<const bf16x8*>(qrow + 32);
    }

    const int krow = tid >> 2;            // 0..63 (this thread: rows krow, krow+64)
    const int kcb  = (tid & 3) << 4;      // bf16 offset 0,16,32,48
    const int vkb  = (tid & 15) << 2;     // V k base within a 64-half
    const int vdb  = (tid >> 4) << 2;     // V d base (4 consecutive d)
    const int q16  = tid & 15;            // k-quad id within half
    const int voff = ((q16 & 3) << 5) | ((q16 >> 2) << 2);  // half 0; half1 = +16

    // wave-uniform bases into the packed mask array (qw = q0/16 + 2w + qi)
    const int wbase0 = __builtin_amdgcn_readfirstlane(
        (bb * 128 + (q0 >> 4) + (w << 1)) << 9);
    const int wbase1 = wbase0 + 512;

    // all-ones bf16 B-fragment for the rowsum MFMA
    union { unsigned u[4]; bf16x8 v; } onesu;
#pragma unroll
    for (int j = 0; j < 4; ++j) onesu.u[j] = 0x3F803F80u;
    const bf16x8 onesv = onesu.v;

    f32x4 Lacc[2];
    f32x4 O4[2][4];
#pragma unroll
    for (int qi = 0; qi < 2; ++qi) {
        Lacc[qi] = (f32x4){0.f, 0.f, 0.f, 0.f};
#pragma unroll
        for (int db = 0; db < 4; ++db) O4[qi][db] = (f32x4){0.f, 0.f, 0.f, 0.f};
    }

    // prologue: prefetch 128-row tile 0 into registers
    uint4 kv0a = *reinterpret_cast<const uint4*>(Kh + (size_t)krow * DK + kcb);
    uint4 kv1a = *reinterpret_cast<const uint4*>(Kh + (size_t)krow * DK + kcb + 8);
    uint4 kv0b = *reinterpret_cast<const uint4*>(Kh + (size_t)(krow + 64) * DK + kcb);
    uint4 kv1b = *reinterpret_cast<const uint4*>(Kh + (size_t)(krow + 64) * DK + kcb + 8);
    uint2 vra[4], vrb[4];
#pragma unroll
    for (int i = 0; i < 4; ++i) {
        vra[i] = *reinterpret_cast<const uint2*>(Vh + (size_t)(vkb + i) * DK + vdb);
        vrb[i] = *reinterpret_cast<const uint2*>(Vh + (size_t)(64 + vkb + i) * DK + vdb);
    }

#pragma unroll 1
    for (int t = 0; t < NT128; ++t) {
        const int c = t & 1;

        // ---- stage 128-row tile t into buffer c ----
        *reinterpret_cast<uint4*>(&Kbf[c][krow][kcb])          = kv0a;
        *reinterpret_cast<uint4*>(&Kbf[c][krow][kcb + 8])      = kv1a;
        *reinterpret_cast<uint4*>(&Kbf[c][krow + 64][kcb])     = kv0b;
        *reinterpret_cast<uint4*>(&Kbf[c][krow + 64][kcb + 8]) = kv1b;
#pragma unroll
        for (int hf = 0; hf < 2; ++hf) {   // transpose each 64-k half
            const uint2* vr = hf ? vrb : vra;
            const int vo = voff + (hf << 4);
            uint2 o;
            o.x = (vr[0].x & 0xFFFFu) | (vr[1].x << 16);
            o.y = (vr[2].x & 0xFFFFu) | (vr[3].x << 16);
            *reinterpret_cast<uint2*>(&V3[c][vdb + 0][vo]) = o;
            o.x = (vr[0].x >> 16) | (vr[1].x & 0xFFFF0000u);
            o.y = (vr[2].x >> 16) | (vr[3].x & 0xFFFF0000u);
            *reinterpret_cast<uint2*>(&V3[c][vdb + 1][vo]) = o;
            o.x = (vr[0].y & 0xFFFFu) | (vr[1].y << 16);
            o.y = (vr[2].y & 0xFFFFu) | (vr[3].y << 16);
            *reinterpret_cast<uint2*>(&V3[c][vdb + 2][vo]) = o;
            o.x = (vr[0].y >> 16) | (vr[1].y & 0xFFFF0000u);
            o.y = (vr[2].y >> 16) | (vr[3].y & 0xFFFF0000u);
            *reinterpret_cast<uint2*>(&V3[c][vdb + 3][vo]) = o;
        }
        __syncthreads();   // buffer c visible (other buffer free for writes)

        // ---- prefetch NEXT 128-tile (latency hides under this compute) ----
        if (t + 1 < NT128) {
            const int kn = (t + 1) << 7;
            kv0a = *reinterpret_cast<const uint4*>(Kh + (size_t)(kn + krow) * DK + kcb);
            kv1a = *reinterpret_cast<const uint4*>(Kh + (size_t)(kn + krow) * DK + kcb + 8);
            kv0b = *reinterpret_cast<const uint4*>(Kh + (size_t)(kn + krow + 64) * DK + kcb);
            kv1b = *reinterpret_cast<const uint4*>(Kh + (size_t)(kn + krow + 64) * DK + kcb + 8);
#pragma unroll
            for (int i = 0; i < 4; ++i) {
                vra[i] = *reinterpret_cast<const uint2*>(
                    Vh + (size_t)(kn + vkb + i) * DK + vdb);
                vrb[i] = *reinterpret_cast<const uint2*>(
                    Vh + (size_t)(kn + 64 + vkb + i) * DK + vdb);
            }
        }

        // ---- two 64-k subtiles, layouts identical to the verified kernel ----
#pragma unroll
        for (int h = 0; h < 2; ++h) {
            // QK^T both q-tiles, K-fragments read once
            f32x4 S[2][4];
#pragma unroll
            for (int n = 0; n < 4; ++n) {
                const bf16x8 b0 = *reinterpret_cast<const bf16x8*>(
                    &Kbf[c][(h << 6) + 16 * n + l15][kg << 3]);
                const bf16x8 b1 = *reinterpret_cast<const bf16x8*>(
                    &Kbf[c][(h << 6) + 16 * n + l15][(kg << 3) + 32]);
#pragma unroll
                for (int qi = 0; qi < 2; ++qi) {
                    f32x4 acc = (f32x4){0.f, 0.f, 0.f, 0.f};
                    acc = __builtin_amdgcn_mfma_f32_16x16x32_bf16(b0, aq[qi][0], acc, 0, 0, 0);
                    acc = __builtin_amdgcn_mfma_f32_16x16x32_bf16(b1, aq[qi][1], acc, 0, 0, 0);
                    S[qi][n] = acc;
                }
            }

            // softmax per q-tile: P = mask ? exp2(S) : 0 (Q pre-scaled)
            bf16x8 paf[2][2];
#pragma unroll
            for (int qi = 0; qi < 2; ++qi) {
                const unsigned long long* wmt =
                    wmask + (qi ? wbase1 : wbase0) + (((t << 1) | h) << 4);
                unsigned long long wmv[16];
#pragma unroll
                for (int rn = 0; rn < 16; ++rn) wmv[rn] = wmt[rn];

                unsigned pw01[4], pw23[4];
#pragma unroll
                for (int n = 0; n < 4; ++n) {
                    float xv[4];
#pragma unroll
                    for (int r = 0; r < 4; ++r) {
                        float e;
                        __asm__("v_exp_f32 %0, %1" : "=v"(e) : "v"(S[qi][n][r]));
                        __asm__("v_cndmask_b32 %0, 0, %1, %2"
                                : "=v"(e) : "v"(e), "s"(wmv[(r << 2) | n]));
                        xv[r] = e;
                    }
                    __asm__("v_cvt_pk_bf16_f32 %0, %1, %2"
                            : "=v"(pw01[n]) : "v"(xv[0]), "v"(xv[1]));
                    __asm__("v_cvt_pk_bf16_f32 %0, %1, %2"
                            : "=v"(pw23[n]) : "v"(xv[2]), "v"(xv[3]));
                }
                union { unsigned u[4]; bf16x8 v; } pa0, pa1;
                pa0.u[0] = pw01[0]; pa0.u[1] = pw23[0]; pa0.u[2] = pw01[1]; pa0.u[3] = pw23[1];
                pa1.u[0] = pw01[2]; pa1.u[1] = pw23[2]; pa1.u[2] = pw01[3]; pa1.u[3] = pw23[3];
                paf[qi][0] = pa0.v;
                paf[qi][1] = pa1.v;

                // rowsum via MFMA: Lacc[r] += sum over this subtile's 64 k
                Lacc[qi] = __builtin_amdgcn_mfma_f32_16x16x32_bf16(
                    paf[qi][0], onesv, Lacc[qi], 0, 0, 0);
                Lacc[qi] = __builtin_amdgcn_mfma_f32_16x16x32_bf16(
                    paf[qi][1], onesv, Lacc[qi], 0, 0, 0);
            }

            // PV both q-tiles, V-fragments read once
#pragma unroll
            for (int db = 0; db < 4; ++db) {
                const unsigned short* vbase =
                    &V3[c][(db << 4) + l15][(kg << 5) | (h << 4)];
                const bf16x8 v0 = *reinterpret_cast<const bf16x8*>(vbase);
                const bf16x8 v1 = *reinterpret_cast<const bf16x8*>(vbase + 8);
#pragma unroll
                for (int qi = 0; qi < 2; ++qi) {
                    O4[qi][db] = __builtin_amdgcn_mfma_f32_16x16x32_bf16(
                        paf[qi][0], v0, O4[qi][db], 0, 0, 0);
                    O4[qi][db] = __builtin_amdgcn_mfma_f32_16x16x32_bf16(
                        paf[qi][1], v1, O4[qi][db], 0, 0, 0);
                }
            }
        }
    }

    // epilogue: Lacc[qi][r] holds the full row sum for q = 4kg+r (replicated
    // across l15) — normalize and store, no shuffles needed.
#pragma unroll
    for (int qi = 0; qi < 2; ++qi) {
#pragma unroll
        for (int r = 0; r < 4; ++r) {
            const float inv = 1.f / Lacc[qi][r];
            const size_t base =
                (size_t)(bb * SEQ + q0 + w * 32 + qi * 16 + (kg << 2) + r) * D_MODEL
                + hh * DK + l15;
#pragma unroll
            for (int db = 0; db < 4; ++db)
                ctx[base + 16 * db] = f2bf(O4[qi][db][r] * inv);
        }
    }
}

// ---------------------------------------------------------------------------
extern "C" void kernel_launch(void* const* d_in, const int* in_sizes, int n_in,
                              void* d_out, int out_size, void* d_ws, size_t ws_size,
                              hipStream_t stream)
{
    const float* query = (const float*)d_in[0];
    const float* key   = (const float*)d_in[1];
    const float* value = (const float*)d_in[2];
    const int*   mask  = (const int*)d_in[3];
    const float* Wq = (const float*)d_in[4];
    const float* bq = (const float*)d_in[5];
    const float* Wk = (const float*)d_in[6];
    const float* bk = (const float*)d_in[7];
    const float* Wv = (const float*)d_in[8];
    const float* bv = (const float*)d_in[9];
    const float* Wo = (const float*)d_in[10];
    const float* bo = (const float*)d_in[11];

    unsigned short* ws = (unsigned short*)d_ws;
    const size_t TE = (size_t)M_TOTAL * D_MODEL;     // 4,194,304
    const size_t WE = (size_t)D_MODEL * D_MODEL;     // 1,048,576
    unsigned short* Xq  = ws;
    unsigned short* Xk  = Xq + TE;
    unsigned short* Xv  = Xk + TE;
    unsigned short* WTq = Xv + TE;
    unsigned short* WTk = WTq + WE;
    unsigned short* WTv = WTk + WE;
    unsigned short* WTo = WTv + WE;
    unsigned short* Qb  = WTo + WE;
    unsigned short* Kb  = Qb + TE;
    unsigned short* Vb  = Kb + TE;
    unsigned short* Ctx = Vb + TE;                   // ends at 64 MB exactly
    unsigned long long* WM = (unsigned long long*)(Ctx + TE);  // +1 MB packed masks

    PrepArgs pa;
    pa.xs[0] = query; pa.xs[1] = key; pa.xs[2] = value;
    pa.xd[0] = Xq;    pa.xd[1] = Xk;  pa.xd[2] = Xv;
    pa.wsrc[0] = Wq;  pa.wsrc[1] = Wk;  pa.wsrc[2] = Wv;  pa.wsrc[3] = Wo;
    pa.wdst[0] = WTq; pa.wdst[1] = WTk; pa.wdst[2] = WTv; pa.wdst[3] = WTo;
    pa.mask = mask; pa.wm = WM;
    prep_all<<<dim3(18432, 1, 1), 256, 0, stream>>>(pa);

    GArgs<unsigned short> qkv;
    qkv.X[0] = Xq;  qkv.X[1] = Xk;  qkv.X[2] = Xv;
    qkv.W[0] = WTq; qkv.W[1] = WTk; qkv.W[2] = WTv;
    qkv.Bi[0] = bq; qkv.Bi[1] = bk; qkv.Bi[2] = bv;
    qkv.O[0] = Qb;  qkv.O[1] = Kb;  qkv.O[2] = Vb;
    qkv.scl[0] = QSCALE; qkv.scl[1] = 1.f; qkv.scl[2] = 1.f;
    gemm_bf16<unsigned short, 4><<<dim3(8, 32, 3), 256, 0, stream>>>(qkv, 1);

    flash_mfma<<<dim3(SEQ / 128, NHEADS, BATCH), 256, 0, stream>>>(
        Qb, Kb, Vb, WM, Ctx);

    GArgs<float> op;
    op.X[0] = Ctx;  op.X[1] = Ctx;  op.X[2] = Ctx;
    op.W[0] = WTo;  op.W[1] = WTo;  op.W[2] = WTo;
    op.Bi[0] = bo;  op.Bi[1] = bo;  op.Bi[2] = bo;
    op.O[0] = (float*)d_out; op.O[1] = (float*)d_out; op.O[2] = (float*)d_out;
    op.scl[0] = 1.f; op.scl[1] = 1.f; op.scl[2] = 1.f;
    // 64x128 tiles: 8x64 = 512 blocks = 2 blocks/CU
    gemm_bf16<float, 2><<<dim3(8, 64, 1), 256, 0, stream>>>(op, 0);
}